// Round 1
// baseline (1510.002 us; speedup 1.0000x reference)
//
#include <hip/hip_runtime.h>
#include <math.h>

#define N_ROWS 32768
#define M_CODES 2048
#define D_DIM 512

// d_out flat offsets (floats), reference return order
#define OUT_QST       0
#define OUT_COMMIT    16777216
#define OUT_CODEBOOK  16777217
#define OUT_ORTHO     16777218
#define OUT_INDICES   16777219
#define OUT_NEWEMB    16809987
#define OUT_NEWCOUNT  17858563
#define OUT_NEWW      17860611

// ---------------- workspace layout (float offsets) ----------------
// zeroed region: [0, WS_ZERO_FLOATS)
#define WS_COUNTS     0            // 2048
#define WS_DW         2048         // 1048576
#define WS_SSE        1050624      // 1
#define WS_ORTHO      1050625      // 1
#define WS_ZERO_FLOATS 1050626
#define WS_E2         1050632      // 2048
#define WS_X2         1052680      // 32768
#define WS_IDX        1085448      // 32768 (int)
#define WS_NCN        1118216      // 2048
#define WS_SEL        1120264      // 128 (int)
#define WS_VALID      1120392      // 128
#define WS_NVALID     1120520      // 1 (+3 pad)
#define WS_NORMED     1120524      // 65536
#define WS_NORMEDT    1186060      // 65536

// ---------------- squared norms of emb rows and x rows ----------------
__global__ __launch_bounds__(256) void sq_kernel(const float* __restrict__ emb,
                                                 const float* __restrict__ x,
                                                 float* __restrict__ e2,
                                                 float* __restrict__ x2) {
    int row  = blockIdx.x * 4 + (threadIdx.x >> 6);
    int lane = threadIdx.x & 63;
    const float* src = (row < M_CODES) ? (emb + (size_t)row * D_DIM)
                                       : (x + (size_t)(row - M_CODES) * D_DIM);
    float4 a = *(const float4*)(src + lane * 4);
    float4 b = *(const float4*)(src + 256 + lane * 4);
    float s = a.x*a.x + a.y*a.y + a.z*a.z + a.w*a.w
            + b.x*b.x + b.y*b.y + b.z*b.z + b.w*b.w;
#pragma unroll
    for (int o = 32; o > 0; o >>= 1) s += __shfl_xor(s, o, 64);
    if (lane == 0) {
        if (row < M_CODES) e2[row] = s;
        else               x2[row - M_CODES] = s;
    }
}

// ---------------- fp32 distance argmin (the heavy kernel) ----------------
// dist[n][m] = fl( fl(x2[n] + e2[m]) - 2*dot(x[n],e[m]) ), argmin ties -> lowest m.
// Tile: BN=64 rows x BM=64 codes, BK=32; 256 threads, 4x4 per-thread tile.
__global__ __launch_bounds__(256) void argmin_kernel(const float* __restrict__ x,
                                                     const float* __restrict__ emb,
                                                     const float* __restrict__ e2,
                                                     const float* __restrict__ x2,
                                                     int* __restrict__ idx_out,
                                                     float* __restrict__ idxf_out) {
    __shared__ float As[64][36];    // [row][k], +4 pad keeps 16B-aligned rows
    __shared__ float Bs[32][68];    // [k][code], +4 pad
    __shared__ float e2s[64];
    __shared__ float redD[64][17];
    __shared__ int   redI[64][17];

    const int t  = threadIdx.x;
    const int tx = t & 15;          // code group
    const int ty = t >> 4;          // row group
    const int row0 = blockIdx.x * 64;

    float rmin[4];
    int   ridx[4];
#pragma unroll
    for (int r = 0; r < 4; ++r) { rmin[r] = 3.0e38f; ridx[r] = 0; }

    float x2r[4];
#pragma unroll
    for (int r = 0; r < 4; ++r) x2r[r] = x2[row0 + ty * 4 + r];

    const int lr = t >> 3;  // 0..31 staging row
    const int lc = t & 7;   // 0..7  float4 chunk

    for (int m0 = 0; m0 < M_CODES; m0 += 64) {
        __syncthreads();                 // protect e2s reuse across m-tiles
        if (t < 64) e2s[t] = e2[m0 + t];

        float acc[4][4];
#pragma unroll
        for (int r = 0; r < 4; ++r)
#pragma unroll
            for (int c = 0; c < 4; ++c) acc[r][c] = 0.f;

        for (int k0 = 0; k0 < D_DIM; k0 += 32) {
            __syncthreads();             // protect As/Bs from previous compute
#pragma unroll
            for (int p = 0; p < 2; ++p) {
                int r = p * 32 + lr;
                float4 v = *(const float4*)(x + (size_t)(row0 + r) * D_DIM + k0 + lc * 4);
                *(float4*)(&As[r][lc * 4]) = v;
            }
#pragma unroll
            for (int p = 0; p < 2; ++p) {
                int r = p * 32 + lr;     // code within tile
                float4 v = *(const float4*)(emb + (size_t)(m0 + r) * D_DIM + k0 + lc * 4);
                Bs[lc * 4 + 0][r] = v.x;
                Bs[lc * 4 + 1][r] = v.y;
                Bs[lc * 4 + 2][r] = v.z;
                Bs[lc * 4 + 3][r] = v.w;
            }
            __syncthreads();

#pragma unroll
            for (int kk = 0; kk < 32; kk += 4) {
                float av[4][4], bv[4][4];
#pragma unroll
                for (int r = 0; r < 4; ++r) {
                    float4 a4 = *(const float4*)(&As[ty * 4 + r][kk]);
                    av[r][0] = a4.x; av[r][1] = a4.y; av[r][2] = a4.z; av[r][3] = a4.w;
                }
#pragma unroll
                for (int j = 0; j < 4; ++j) {
                    float4 b4 = *(const float4*)(&Bs[kk + j][tx * 4]);
                    bv[j][0] = b4.x; bv[j][1] = b4.y; bv[j][2] = b4.z; bv[j][3] = b4.w;
                }
#pragma unroll
                for (int j = 0; j < 4; ++j)
#pragma unroll
                    for (int r = 0; r < 4; ++r)
#pragma unroll
                        for (int c = 0; c < 4; ++c)
                            acc[r][c] += av[r][j] * bv[j][c];
            }
        }

        // distances for this m-tile; ties keep earliest (lowest m: c ascending, m0 ascending)
#pragma unroll
        for (int c = 0; c < 4; ++c) {
            int mm = tx * 4 + c;
            int m  = m0 + mm;
            float e2v = e2s[mm];
#pragma unroll
            for (int r = 0; r < 4; ++r) {
                float t1 = x2r[r] + e2v;
                float d  = t1 - 2.0f * acc[r][c];   // 2*acc exact; fma == two-step here
                if (d < rmin[r]) { rmin[r] = d; ridx[r] = m; }
            }
        }
    }

    __syncthreads();
#pragma unroll
    for (int r = 0; r < 4; ++r) {
        redD[ty * 4 + r][tx] = rmin[r];
        redI[ty * 4 + r][tx] = ridx[r];
    }
    __syncthreads();
    if (t < 64) {
        float best = redD[t][0];
        int   bi   = redI[t][0];
#pragma unroll
        for (int i = 1; i < 16; ++i) {
            float dd = redD[t][i];
            int   ii = redI[t][i];
            if (dd < best || (dd == best && ii < bi)) { best = dd; bi = ii; }
        }
        idx_out[row0 + t]  = bi;
        idxf_out[row0 + t] = (float)bi;
    }
}

// ---------------- scatter: counts, dw, quant_st, SSE ----------------
__global__ __launch_bounds__(256) void scatter_kernel(const float* __restrict__ x,
                                                      const float* __restrict__ emb,
                                                      const int* __restrict__ idx,
                                                      float* __restrict__ counts,
                                                      float* __restrict__ dw,
                                                      float* __restrict__ sse,
                                                      float* __restrict__ qst) {
    const int w    = threadIdx.x >> 6;
    const int lane = threadIdx.x & 63;
    const int rowbase = blockIdx.x * 16 + w * 4;
    float loss = 0.f;
    for (int i = 0; i < 4; ++i) {
        const int row = rowbase + i;
        const int m   = idx[row];
        if (lane == 0) atomicAdd(&counts[m], 1.0f);
#pragma unroll
        for (int j = 0; j < 2; ++j) {
            const int off = j * 256 + lane * 4;
            float4 xv = *(const float4*)(x + (size_t)row * D_DIM + off);
            float4 qv = *(const float4*)(emb + (size_t)m * D_DIM + off);
            float4 qs;
            qs.x = xv.x + (qv.x - xv.x);
            qs.y = xv.y + (qv.y - xv.y);
            qs.z = xv.z + (qv.z - xv.z);
            qs.w = xv.w + (qv.w - xv.w);
            *(float4*)(qst + (size_t)row * D_DIM + off) = qs;
            float dx;
            dx = xv.x - qv.x; loss += dx * dx;
            dx = xv.y - qv.y; loss += dx * dx;
            dx = xv.z - qv.z; loss += dx * dx;
            dx = xv.w - qv.w; loss += dx * dx;
            atomicAdd(dw + (size_t)m * D_DIM + off + 0, xv.x);
            atomicAdd(dw + (size_t)m * D_DIM + off + 1, xv.y);
            atomicAdd(dw + (size_t)m * D_DIM + off + 2, xv.z);
            atomicAdd(dw + (size_t)m * D_DIM + off + 3, xv.w);
        }
    }
#pragma unroll
    for (int o = 32; o > 0; o >>= 1) loss += __shfl_xor(loss, o, 64);
    if (lane == 0) atomicAdd(sse, loss);
}

// ---------------- EMA count + Laplace normalize ----------------
__global__ __launch_bounds__(256) void f1_kernel(const float* __restrict__ ema_count,
                                                 const float* __restrict__ counts,
                                                 float* __restrict__ out_newcount,
                                                 float* __restrict__ nc_ws) {
    __shared__ float red[256];
    int t = threadIdx.x;
    float raw[8];
    float part = 0.f;
#pragma unroll
    for (int i = 0; i < 8; ++i) {
        int m = t * 8 + i;
        raw[i] = 0.999f * ema_count[m] + 0.001f * counts[m];
        part += raw[i];
    }
    red[t] = part;
    __syncthreads();
    for (int s = 128; s > 0; s >>= 1) {
        if (t < s) red[t] += red[t + s];
        __syncthreads();
    }
    float n = red[0];
    float denom = n + (float)M_CODES * 1e-5f;
#pragma unroll
    for (int i = 0; i < 8; ++i) {
        int m = t * 8 + i;
        float v = (raw[i] + 1e-5f) / denom * n;
        out_newcount[m] = v;
        nc_ws[m] = v;
    }
}

// ---------------- EMA weight + new embedding ----------------
__global__ __launch_bounds__(256) void f2_kernel(const float* __restrict__ ema_weight,
                                                 const float* __restrict__ dw,
                                                 const float* __restrict__ nc,
                                                 float* __restrict__ out_ne,
                                                 float* __restrict__ out_nw) {
    size_t i = ((size_t)blockIdx.x * 256 + threadIdx.x) * 4;
    int m = (int)(i >> 9);
    float4 wv = *(const float4*)(ema_weight + i);
    float4 dv = *(const float4*)(dw + i);
    float  c  = nc[m];
    float4 nw, ne;
    nw.x = 0.999f * wv.x + 0.001f * dv.x; ne.x = nw.x / c;
    nw.y = 0.999f * wv.y + 0.001f * dv.y; ne.y = nw.y / c;
    nw.z = 0.999f * wv.z + 0.001f * dv.z; ne.z = nw.z / c;
    nw.w = 0.999f * wv.w + 0.001f * dv.w; ne.w = nw.w / c;
    *(float4*)(out_nw + i) = nw;
    *(float4*)(out_ne + i) = ne;
}

// ---------------- stable compaction (used-first), normalize rows ----------------
__global__ __launch_bounds__(256) void g1_kernel(const float* __restrict__ counts,
                                                 const float* __restrict__ new_emb,
                                                 int* __restrict__ sel,
                                                 float* __restrict__ valid,
                                                 float* __restrict__ n_valid,
                                                 float* __restrict__ normed,
                                                 float* __restrict__ normedT) {
    __shared__ int pre[257];
    int t = threadIdx.x;
    int u = 0;
#pragma unroll
    for (int i = 0; i < 8; ++i) u += (counts[t * 8 + i] > 0.f) ? 1 : 0;
    pre[t] = u;
    __syncthreads();
    if (t == 0) {
        int run = 0;
        for (int i = 0; i < 256; ++i) { int c = pre[i]; pre[i] = run; run += c; }
        pre[256] = run;
    }
    __syncthreads();
    int U = pre[256];
    int base = pre[t];
    int run = 0;
    for (int i = 0; i < 8; ++i) {
        int m = t * 8 + i;
        bool used = counts[m] > 0.f;
        int ur = base + run;                 // # used with index < m
        if (used) {
            if (ur < 128) sel[ur] = m;
            run++;
        } else {
            int pos = U + (m - ur);          // U + unused-rank
            if (pos < 128) sel[pos] = m;
        }
    }
    __syncthreads();
    if (t < 128) valid[t] = (counts[sel[t]] > 0.f) ? 1.f : 0.f;
    __syncthreads();
    if (t == 0) {
        float s = 0.f;
        for (int i = 0; i < 128; ++i) s += valid[i];
        *n_valid = s;
    }
    int w = t >> 6, lane = t & 63;
    for (int r = w; r < 128; r += 4) {
        int sm = sel[r];
        const float* src = new_emb + (size_t)sm * D_DIM;
        float4 a = *(const float4*)(src + lane * 4);
        float4 b = *(const float4*)(src + 256 + lane * 4);
        float s = a.x*a.x + a.y*a.y + a.z*a.z + a.w*a.w
                + b.x*b.x + b.y*b.y + b.z*b.z + b.w*b.w;
#pragma unroll
        for (int o = 32; o > 0; o >>= 1) s += __shfl_xor(s, o, 64);
        float norm = fmaxf(sqrtf(s), 1e-12f);
        float vv = valid[r];
        float4 na, nb;
        na.x = a.x / norm * vv; na.y = a.y / norm * vv;
        na.z = a.z / norm * vv; na.w = a.w / norm * vv;
        nb.x = b.x / norm * vv; nb.y = b.y / norm * vv;
        nb.z = b.z / norm * vv; nb.w = b.w / norm * vv;
        *(float4*)(normed + (size_t)r * D_DIM + lane * 4) = na;
        *(float4*)(normed + (size_t)r * D_DIM + 256 + lane * 4) = nb;
        normedT[(lane * 4 + 0) * 128 + r] = na.x;
        normedT[(lane * 4 + 1) * 128 + r] = na.y;
        normedT[(lane * 4 + 2) * 128 + r] = na.z;
        normedT[(lane * 4 + 3) * 128 + r] = na.w;
        normedT[(256 + lane * 4 + 0) * 128 + r] = nb.x;
        normedT[(256 + lane * 4 + 1) * 128 + r] = nb.y;
        normedT[(256 + lane * 4 + 2) * 128 + r] = nb.z;
        normedT[(256 + lane * 4 + 3) * 128 + r] = nb.w;
    }
}

// ---------------- cosine-sim loss accumulation ----------------
__global__ __launch_bounds__(128) void g2_kernel(const float* __restrict__ normed,
                                                 const float* __restrict__ normedT,
                                                 const float* __restrict__ valid,
                                                 float* __restrict__ ortho_acc) {
    __shared__ float rowi[512];
    __shared__ float red[128];
    int i = blockIdx.x, t = threadIdx.x;
    *(float4*)(rowi + t * 4) = *(const float4*)(normed + (size_t)i * D_DIM + t * 4);
    __syncthreads();
    float dot = 0.f;
    for (int k = 0; k < D_DIM; ++k) dot += rowi[k] * normedT[k * 128 + t];
    float diag = (i == t) ? valid[i] : 0.f;
    float d = dot - diag;
    red[t] = d * d;
    __syncthreads();
    for (int s = 64; s > 0; s >>= 1) {
        if (t < s) red[t] += red[t + s];
        __syncthreads();
    }
    if (t == 0) atomicAdd(ortho_acc, red[0]);
}

// ---------------- final scalars ----------------
__global__ void g3_kernel(const float* __restrict__ sse,
                          const float* __restrict__ ortho_acc,
                          const float* __restrict__ n_valid,
                          float* __restrict__ out3) {
    if (threadIdx.x == 0 && blockIdx.x == 0) {
        float m = *sse / 16777216.f;
        out3[0] = 0.25f * m;            // commitment_loss
        out3[1] = m;                    // codebook_loss
        float nv = *n_valid;
        out3[2] = *ortho_acc / (nv * nv) * 10.f;   // ortho_loss
    }
}

extern "C" void kernel_launch(void* const* d_in, const int* in_sizes, int n_in,
                              void* d_out, int out_size, void* d_ws, size_t ws_size,
                              hipStream_t stream) {
    const float* x          = (const float*)d_in[0];
    const float* emb        = (const float*)d_in[1];
    const float* ema_count  = (const float*)d_in[2];
    const float* ema_weight = (const float*)d_in[3];
    float* out = (float*)d_out;
    float* ws  = (float*)d_ws;

    float* counts  = ws + WS_COUNTS;
    float* dw      = ws + WS_DW;
    float* sse     = ws + WS_SSE;
    float* ortho   = ws + WS_ORTHO;
    float* e2      = ws + WS_E2;
    float* x2      = ws + WS_X2;
    int*   idxws   = (int*)(ws + WS_IDX);
    float* ncn     = ws + WS_NCN;
    int*   sel     = (int*)(ws + WS_SEL);
    float* valid   = ws + WS_VALID;
    float* nvalid  = ws + WS_NVALID;
    float* normed  = ws + WS_NORMED;
    float* normedT = ws + WS_NORMEDT;

    hipMemsetAsync(ws, 0, (size_t)WS_ZERO_FLOATS * sizeof(float), stream);

    sq_kernel<<<(M_CODES + N_ROWS) / 4, 256, 0, stream>>>(emb, x, e2, x2);

    argmin_kernel<<<N_ROWS / 64, 256, 0, stream>>>(x, emb, e2, x2, idxws,
                                                   out + OUT_INDICES);

    scatter_kernel<<<N_ROWS / 16, 256, 0, stream>>>(x, emb, idxws, counts, dw, sse,
                                                    out + OUT_QST);

    f1_kernel<<<1, 256, 0, stream>>>(ema_count, counts, out + OUT_NEWCOUNT, ncn);

    f2_kernel<<<(M_CODES * D_DIM) / (256 * 4), 256, 0, stream>>>(ema_weight, dw, ncn,
                                                                 out + OUT_NEWEMB,
                                                                 out + OUT_NEWW);

    g1_kernel<<<1, 256, 0, stream>>>(counts, out + OUT_NEWEMB, sel, valid, nvalid,
                                     normed, normedT);

    g2_kernel<<<128, 128, 0, stream>>>(normed, normedT, valid, ortho);

    g3_kernel<<<1, 64, 0, stream>>>(sse, ortho, nvalid, out + OUT_COMMIT);
}

// Round 2
// 839.544 us; speedup vs baseline: 1.7986x; 1.7986x over previous
//
#include <hip/hip_runtime.h>
#include <math.h>

#define N_ROWS 32768
#define M_CODES 2048
#define D_DIM 512
#define MARGIN 2.5e-4f
#define CAND_CAP 24

// d_out flat offsets (floats), reference return order
#define OUT_QST       0
#define OUT_COMMIT    16777216
#define OUT_CODEBOOK  16777217
#define OUT_ORTHO     16777218
#define OUT_INDICES   16777219
#define OUT_NEWEMB    16809987
#define OUT_NEWCOUNT  17858563
#define OUT_NEWW      17860611

// ---------------- workspace layout (float offsets) ----------------
// zeroed region: [0, WS_ZERO_FLOATS)
#define WS_COUNTS     0            // 2048
#define WS_DW         2048         // 1048576
#define WS_SSE        1050624      // 1
#define WS_ORTHO      1050625     // 1 (+6 pad)
#define WS_CANDCNT    1050632      // 32768 ints
#define WS_ZERO_FLOATS 1083400
#define WS_E2         1083400      // 2048
#define WS_X2         1085448      // 32768
#define WS_IDX        1118216      // 32768 (int)
#define WS_NCN        1150984      // 2048
#define WS_SEL        1153032      // 128 (int)
#define WS_VALID      1153160     // 128
#define WS_NVALID     1153288     // 1 (+7 pad)
#define WS_NORMED     1153296     // 65536
#define WS_NORMEDT    1218832     // 65536
#define WS_CANDC      1284368     // 32768*24 ints
#define WS_CANDD      2070800     // 32768*24 floats
#define WS_XH         2857232     // 32768*512 shorts (8388608 float slots)
#define WS_XL         11245840
#define WS_EH         19634448    // 2048*512 shorts (524288 float slots)
#define WS_EL         20158736
#define WS_TOTAL_FLOATS 20683024

typedef __attribute__((ext_vector_type(8))) short short8v;
typedef __attribute__((ext_vector_type(4))) float f32x4;

__device__ __forceinline__ unsigned short f2bf(float f) {
    unsigned u = __float_as_uint(f);
    unsigned r = (u + 0x7fffu + ((u >> 16) & 1u)) >> 16;
    return (unsigned short)r;
}
__device__ __forceinline__ float bf2f(unsigned short s) {
    return __uint_as_float(((unsigned)s) << 16);
}
__device__ __forceinline__ int fkey(float f) {
    int b = __float_as_int(f);
    return b >= 0 ? b : (b ^ 0x7fffffff);
}
__device__ __forceinline__ float kinv(int k) {
    int b = k >= 0 ? k : (k ^ 0x7fffffff);
    return __int_as_float(b);
}

#define GLOAD16(g, s) __builtin_amdgcn_global_load_lds( \
    (const __attribute__((address_space(1))) void*)(g), \
    (__attribute__((address_space(3))) void*)(s), 16, 0, 0)

// ---------------- prep: e2/x2 + bf16 splits (main path) ----------------
__global__ __launch_bounds__(256) void prep_kernel(const float* __restrict__ emb,
                                                   const float* __restrict__ x,
                                                   float* __restrict__ e2,
                                                   float* __restrict__ x2,
                                                   unsigned short* __restrict__ xh,
                                                   unsigned short* __restrict__ xl,
                                                   unsigned short* __restrict__ eh,
                                                   unsigned short* __restrict__ el) {
    int row  = blockIdx.x * 4 + (threadIdx.x >> 6);
    int lane = threadIdx.x & 63;
    bool is_e = row < M_CODES;
    const float* src = is_e ? (emb + (size_t)row * D_DIM)
                            : (x + (size_t)(row - M_CODES) * D_DIM);
    unsigned short* dh = is_e ? (eh + (size_t)row * D_DIM)
                              : (xh + (size_t)(row - M_CODES) * D_DIM);
    unsigned short* dl = is_e ? (el + (size_t)row * D_DIM)
                              : (xl + (size_t)(row - M_CODES) * D_DIM);
    float4 a = *(const float4*)(src + lane * 4);
    float4 b = *(const float4*)(src + 256 + lane * 4);
    float s = a.x*a.x + a.y*a.y + a.z*a.z + a.w*a.w
            + b.x*b.x + b.y*b.y + b.z*b.z + b.w*b.w;
#pragma unroll
    for (int o = 32; o > 0; o >>= 1) s += __shfl_xor(s, o, 64);

    ushort4 h0, l0, h1, l1;
    {
        float v;
        v = a.x; h0.x = f2bf(v); l0.x = f2bf(v - bf2f(h0.x));
        v = a.y; h0.y = f2bf(v); l0.y = f2bf(v - bf2f(h0.y));
        v = a.z; h0.z = f2bf(v); l0.z = f2bf(v - bf2f(h0.z));
        v = a.w; h0.w = f2bf(v); l0.w = f2bf(v - bf2f(h0.w));
        v = b.x; h1.x = f2bf(v); l1.x = f2bf(v - bf2f(h1.x));
        v = b.y; h1.y = f2bf(v); l1.y = f2bf(v - bf2f(h1.y));
        v = b.z; h1.z = f2bf(v); l1.z = f2bf(v - bf2f(h1.z));
        v = b.w; h1.w = f2bf(v); l1.w = f2bf(v - bf2f(h1.w));
    }
    *(ushort4*)(dh + lane * 4)       = h0;
    *(ushort4*)(dl + lane * 4)       = l0;
    *(ushort4*)(dh + 256 + lane * 4) = h1;
    *(ushort4*)(dl + 256 + lane * 4) = l1;

    if (lane == 0) {
        if (is_e) e2[row] = s;
        else      x2[row - M_CODES] = s;
    }
}

// ---------------- sq only (fallback path) ----------------
__global__ __launch_bounds__(256) void sq_kernel(const float* __restrict__ emb,
                                                 const float* __restrict__ x,
                                                 float* __restrict__ e2,
                                                 float* __restrict__ x2) {
    int row  = blockIdx.x * 4 + (threadIdx.x >> 6);
    int lane = threadIdx.x & 63;
    const float* src = (row < M_CODES) ? (emb + (size_t)row * D_DIM)
                                       : (x + (size_t)(row - M_CODES) * D_DIM);
    float4 a = *(const float4*)(src + lane * 4);
    float4 b = *(const float4*)(src + 256 + lane * 4);
    float s = a.x*a.x + a.y*a.y + a.z*a.z + a.w*a.w
            + b.x*b.x + b.y*b.y + b.z*b.z + b.w*b.w;
#pragma unroll
    for (int o = 32; o > 0; o >>= 1) s += __shfl_xor(s, o, 64);
    if (lane == 0) {
        if (row < M_CODES) e2[row] = s;
        else               x2[row - M_CODES] = s;
    }
}

// ---------------- MFMA split-bf16 approx distances + candidate collection ----------------
// Block: 128 rows x 512 codes (4 code-tiles of 128). d = e2[c] - 2*dot_split.
// Per-row prefix-min in LDS; appends (code, d) for d <= min + MARGIN.
__global__ __launch_bounds__(256) void approx_kernel(const unsigned short* __restrict__ xh,
                                                     const unsigned short* __restrict__ xl,
                                                     const unsigned short* __restrict__ eh,
                                                     const unsigned short* __restrict__ el,
                                                     const float* __restrict__ e2g,
                                                     int* __restrict__ candcnt,
                                                     int* __restrict__ candC,
                                                     float* __restrict__ candD) {
    __shared__ short Ah[4096], Al[4096], Bh[4096], Bl[4096]; // [128][32] bf16 each
    __shared__ int rowminI[128];

    const int t = threadIdx.x;
    const int w = t >> 6;        // wave 0..3
    const int l = t & 63;
    const int ml = l & 15;
    const int q  = l >> 4;
    const int rw = (w & 1) * 64; // wave row block
    const int cw = (w >> 1) * 64; // wave col block

    // XCD-aware swizzle: same row-tile's 4 code-quarters land on the same XCD.
    const int bid = blockIdx.x;
    const int row_tile = (bid >> 5) * 8 + (bid & 7);
    const int sub = (bid >> 3) & 3;
    const int row0 = row_tile * 128;
    const int code_base = sub * 512;

    if (t < 128) rowminI[t] = 0x7fffffff;

    const int chunk0 = w * 2;     // staging chunks for this wave
    const int srow = l >> 2;      // 0..15 row within chunk
    const int sc4  = l & 3;       // 16B piece within 64B row

    for (int ct = 0; ct < 4; ++ct) {
        const int code0 = code_base + ct * 128;

        f32x4 acc[4][4];
#pragma unroll
        for (int mi = 0; mi < 4; ++mi)
#pragma unroll
            for (int ni = 0; ni < 4; ++ni) acc[mi][ni] = (f32x4)0.f;

        for (int k0 = 0; k0 < D_DIM; k0 += 32) {
            __syncthreads();
#pragma unroll
            for (int i = 0; i < 2; ++i) {
                int chunk = chunk0 + i;
                int arow = row0 + chunk * 16 + srow;
                int brow = code0 + chunk * 16 + srow;
                size_t ga = (size_t)arow * D_DIM + k0 + sc4 * 8;
                size_t gb = (size_t)brow * D_DIM + k0 + sc4 * 8;
                GLOAD16(xh + ga, &Ah[chunk * 512]);
                GLOAD16(xl + ga, &Al[chunk * 512]);
                GLOAD16(eh + gb, &Bh[chunk * 512]);
                GLOAD16(el + gb, &Bl[chunk * 512]);
            }
            __syncthreads();

            short8v ah[4], al[4];
#pragma unroll
            for (int mi = 0; mi < 4; ++mi) {
                int off = (rw + mi * 16 + ml) * 32 + q * 8;
                ah[mi] = *(const short8v*)(&Ah[off]);
                al[mi] = *(const short8v*)(&Al[off]);
            }
#pragma unroll
            for (int ni = 0; ni < 4; ++ni) {
                int off = (cw + ni * 16 + ml) * 32 + q * 8;
                short8v bh = *(const short8v*)(&Bh[off]);
                short8v bl = *(const short8v*)(&Bl[off]);
#pragma unroll
                for (int mi = 0; mi < 4; ++mi)
                    acc[mi][ni] = __builtin_amdgcn_mfma_f32_16x16x32_bf16(ah[mi], bh, acc[mi][ni], 0, 0, 0);
#pragma unroll
                for (int mi = 0; mi < 4; ++mi)
                    acc[mi][ni] = __builtin_amdgcn_mfma_f32_16x16x32_bf16(ah[mi], bl, acc[mi][ni], 0, 0, 0);
#pragma unroll
                for (int mi = 0; mi < 4; ++mi)
                    acc[mi][ni] = __builtin_amdgcn_mfma_f32_16x16x32_bf16(al[mi], bh, acc[mi][ni], 0, 0, 0);
            }
        }

        // epilogue: d = e2 - 2*acc (in place), per-row min, then candidate appends
        float e2v[4];
#pragma unroll
        for (int ni = 0; ni < 4; ++ni) e2v[ni] = e2g[code0 + cw + ni * 16 + ml];

#pragma unroll
        for (int mi = 0; mi < 4; ++mi)
#pragma unroll
            for (int ni = 0; ni < 4; ++ni)
#pragma unroll
                for (int r = 0; r < 4; ++r)
                    acc[mi][ni][r] = e2v[ni] - 2.0f * acc[mi][ni][r];

#pragma unroll
        for (int mi = 0; mi < 4; ++mi)
#pragma unroll
            for (int r = 0; r < 4; ++r) {
                float v = fminf(fminf(acc[mi][0][r], acc[mi][1][r]),
                                fminf(acc[mi][2][r], acc[mi][3][r]));
#pragma unroll
                for (int o = 1; o < 16; o <<= 1) v = fminf(v, __shfl_xor(v, o, 64));
                if (ml == 0) atomicMin(&rowminI[rw + mi * 16 + q * 4 + r], fkey(v));
            }
        __syncthreads();

#pragma unroll
        for (int mi = 0; mi < 4; ++mi)
#pragma unroll
            for (int r = 0; r < 4; ++r) {
                int row_l = rw + mi * 16 + q * 4 + r;
                float rm = kinv(rowminI[row_l]);
                int row_g = row0 + row_l;
#pragma unroll
                for (int ni = 0; ni < 4; ++ni) {
                    float d = acc[mi][ni][r];
                    if (d <= rm + MARGIN) {
                        int pos = atomicAdd(&candcnt[row_g], 1);
                        if (pos < CAND_CAP) {
                            candC[row_g * CAND_CAP + pos] = code0 + cw + ni * 16 + ml;
                            candD[row_g * CAND_CAP + pos] = d;
                        }
                    }
                }
            }
    }
}

// ---------------- exact re-rank of candidates (replicates round-1 fp32 semantics) ----------------
__global__ __launch_bounds__(256) void rerank_kernel(const float* __restrict__ x,
                                                     const float* __restrict__ emb,
                                                     const float* __restrict__ e2,
                                                     const float* __restrict__ x2,
                                                     const int* __restrict__ candcnt,
                                                     const int* __restrict__ candC,
                                                     const float* __restrict__ candD,
                                                     int* __restrict__ idx_out,
                                                     float* __restrict__ idxf_out) {
    const int w = threadIdx.x >> 6;
    const int lane = threadIdx.x & 63;
    const int row = blockIdx.x * 4 + w;

    int cnt = candcnt[row];
    cnt = cnt < CAND_CAP ? cnt : CAND_CAP;
    float d = 3.0e38f;
    int   c = 0x7fffffff;
    if (lane < cnt) {
        d = candD[row * CAND_CAP + lane];
        c = candC[row * CAND_CAP + lane];
    }
    float dmin = d;
#pragma unroll
    for (int o = 32; o > 0; o >>= 1) dmin = fminf(dmin, __shfl_xor(dmin, o, 64));

    bool surv = (lane < cnt) && (d <= dmin + MARGIN);
    unsigned long long mask = __ballot(surv);

    int best_c;
    if (__popcll(mask) == 1) {
        int src = __ffsll((long long)mask) - 1;
        best_c = __shfl(c, src, 64);
    } else {
        float bd = 3.0e38f;
        int   bc = 0x7fffffff;
        unsigned long long m = mask;
        const float x2r = x2[row];
        const float* xr = x + (size_t)row * D_DIM;
        while (m) {
            int src = __ffsll((long long)m) - 1;
            m &= m - 1;
            int cs = __shfl(c, src, 64);
            // exact fp32 distance, replicating the sequential-fma dot order
            const float* er = emb + (size_t)cs * D_DIM;
            float dot = 0.f;
            for (int k = 0; k < D_DIM; ++k) dot = fmaf(xr[k], er[k], dot);
            float t1 = x2r + e2[cs];
            float dex = t1 - 2.0f * dot;
            if (dex < bd || (dex == bd && cs < bc)) { bd = dex; bc = cs; }
        }
        best_c = bc;
    }
    if (lane == 0) {
        idx_out[row] = best_c;
        idxf_out[row] = (float)best_c;
    }
}

// ---------------- fallback fp32 argmin (round-1 kernel, used if ws too small) ----------------
__global__ __launch_bounds__(256) void argmin_kernel(const float* __restrict__ x,
                                                     const float* __restrict__ emb,
                                                     const float* __restrict__ e2,
                                                     const float* __restrict__ x2,
                                                     int* __restrict__ idx_out,
                                                     float* __restrict__ idxf_out) {
    __shared__ float As[64][36];
    __shared__ float Bs[32][68];
    __shared__ float e2s[64];
    __shared__ float redD[64][17];
    __shared__ int   redI[64][17];

    const int t  = threadIdx.x;
    const int tx = t & 15;
    const int ty = t >> 4;
    const int row0 = blockIdx.x * 64;

    float rmin[4];
    int   ridx[4];
#pragma unroll
    for (int r = 0; r < 4; ++r) { rmin[r] = 3.0e38f; ridx[r] = 0; }

    float x2r[4];
#pragma unroll
    for (int r = 0; r < 4; ++r) x2r[r] = x2[row0 + ty * 4 + r];

    const int lr = t >> 3;
    const int lc = t & 7;

    for (int m0 = 0; m0 < M_CODES; m0 += 64) {
        __syncthreads();
        if (t < 64) e2s[t] = e2[m0 + t];

        float acc[4][4];
#pragma unroll
        for (int r = 0; r < 4; ++r)
#pragma unroll
            for (int c = 0; c < 4; ++c) acc[r][c] = 0.f;

        for (int k0 = 0; k0 < D_DIM; k0 += 32) {
            __syncthreads();
#pragma unroll
            for (int p = 0; p < 2; ++p) {
                int r = p * 32 + lr;
                float4 v = *(const float4*)(x + (size_t)(row0 + r) * D_DIM + k0 + lc * 4);
                *(float4*)(&As[r][lc * 4]) = v;
            }
#pragma unroll
            for (int p = 0; p < 2; ++p) {
                int r = p * 32 + lr;
                float4 v = *(const float4*)(emb + (size_t)(m0 + r) * D_DIM + k0 + lc * 4);
                Bs[lc * 4 + 0][r] = v.x;
                Bs[lc * 4 + 1][r] = v.y;
                Bs[lc * 4 + 2][r] = v.z;
                Bs[lc * 4 + 3][r] = v.w;
            }
            __syncthreads();

#pragma unroll
            for (int kk = 0; kk < 32; kk += 4) {
                float av[4][4], bv[4][4];
#pragma unroll
                for (int r = 0; r < 4; ++r) {
                    float4 a4 = *(const float4*)(&As[ty * 4 + r][kk]);
                    av[r][0] = a4.x; av[r][1] = a4.y; av[r][2] = a4.z; av[r][3] = a4.w;
                }
#pragma unroll
                for (int j = 0; j < 4; ++j) {
                    float4 b4 = *(const float4*)(&Bs[kk + j][tx * 4]);
                    bv[j][0] = b4.x; bv[j][1] = b4.y; bv[j][2] = b4.z; bv[j][3] = b4.w;
                }
#pragma unroll
                for (int j = 0; j < 4; ++j)
#pragma unroll
                    for (int r = 0; r < 4; ++r)
#pragma unroll
                        for (int c = 0; c < 4; ++c)
                            acc[r][c] += av[r][j] * bv[j][c];
            }
        }

#pragma unroll
        for (int c = 0; c < 4; ++c) {
            int mm = tx * 4 + c;
            int m  = m0 + mm;
            float e2v = e2s[mm];
#pragma unroll
            for (int r = 0; r < 4; ++r) {
                float t1 = x2r[r] + e2v;
                float dd  = t1 - 2.0f * acc[r][c];
                if (dd < rmin[r]) { rmin[r] = dd; ridx[r] = m; }
            }
        }
    }

    __syncthreads();
#pragma unroll
    for (int r = 0; r < 4; ++r) {
        redD[ty * 4 + r][tx] = rmin[r];
        redI[ty * 4 + r][tx] = ridx[r];
    }
    __syncthreads();
    if (t < 64) {
        float best = redD[t][0];
        int   bi   = redI[t][0];
#pragma unroll
        for (int i = 1; i < 16; ++i) {
            float dd = redD[t][i];
            int   ii = redI[t][i];
            if (dd < best || (dd == best && ii < bi)) { best = dd; bi = ii; }
        }
        idx_out[row0 + t]  = bi;
        idxf_out[row0 + t] = (float)bi;
    }
}

// ---------------- scatter: counts, dw, quant_st, SSE ----------------
__global__ __launch_bounds__(256) void scatter_kernel(const float* __restrict__ x,
                                                      const float* __restrict__ emb,
                                                      const int* __restrict__ idx,
                                                      float* __restrict__ counts,
                                                      float* __restrict__ dw,
                                                      float* __restrict__ sse,
                                                      float* __restrict__ qst) {
    const int w    = threadIdx.x >> 6;
    const int lane = threadIdx.x & 63;
    const int rowbase = blockIdx.x * 16 + w * 4;
    float loss = 0.f;
    for (int i = 0; i < 4; ++i) {
        const int row = rowbase + i;
        const int m   = idx[row];
        if (lane == 0) atomicAdd(&counts[m], 1.0f);
#pragma unroll
        for (int j = 0; j < 2; ++j) {
            const int off = j * 256 + lane * 4;
            float4 xv = *(const float4*)(x + (size_t)row * D_DIM + off);
            float4 qv = *(const float4*)(emb + (size_t)m * D_DIM + off);
            float4 qs;
            qs.x = xv.x + (qv.x - xv.x);
            qs.y = xv.y + (qv.y - xv.y);
            qs.z = xv.z + (qv.z - xv.z);
            qs.w = xv.w + (qv.w - xv.w);
            *(float4*)(qst + (size_t)row * D_DIM + off) = qs;
            float dx;
            dx = xv.x - qv.x; loss += dx * dx;
            dx = xv.y - qv.y; loss += dx * dx;
            dx = xv.z - qv.z; loss += dx * dx;
            dx = xv.w - qv.w; loss += dx * dx;
            atomicAdd(dw + (size_t)m * D_DIM + off + 0, xv.x);
            atomicAdd(dw + (size_t)m * D_DIM + off + 1, xv.y);
            atomicAdd(dw + (size_t)m * D_DIM + off + 2, xv.z);
            atomicAdd(dw + (size_t)m * D_DIM + off + 3, xv.w);
        }
    }
#pragma unroll
    for (int o = 32; o > 0; o >>= 1) loss += __shfl_xor(loss, o, 64);
    if (lane == 0) atomicAdd(sse, loss);
}

// ---------------- EMA count + Laplace normalize ----------------
__global__ __launch_bounds__(256) void f1_kernel(const float* __restrict__ ema_count,
                                                 const float* __restrict__ counts,
                                                 float* __restrict__ out_newcount,
                                                 float* __restrict__ nc_ws) {
    __shared__ float red[256];
    int t = threadIdx.x;
    float raw[8];
    float part = 0.f;
#pragma unroll
    for (int i = 0; i < 8; ++i) {
        int m = t * 8 + i;
        raw[i] = 0.999f * ema_count[m] + 0.001f * counts[m];
        part += raw[i];
    }
    red[t] = part;
    __syncthreads();
    for (int s = 128; s > 0; s >>= 1) {
        if (t < s) red[t] += red[t + s];
        __syncthreads();
    }
    float n = red[0];
    float denom = n + (float)M_CODES * 1e-5f;
#pragma unroll
    for (int i = 0; i < 8; ++i) {
        int m = t * 8 + i;
        float v = (raw[i] + 1e-5f) / denom * n;
        out_newcount[m] = v;
        nc_ws[m] = v;
    }
}

// ---------------- EMA weight + new embedding ----------------
__global__ __launch_bounds__(256) void f2_kernel(const float* __restrict__ ema_weight,
                                                 const float* __restrict__ dw,
                                                 const float* __restrict__ nc,
                                                 float* __restrict__ out_ne,
                                                 float* __restrict__ out_nw) {
    size_t i = ((size_t)blockIdx.x * 256 + threadIdx.x) * 4;
    int m = (int)(i >> 9);
    float4 wv = *(const float4*)(ema_weight + i);
    float4 dv = *(const float4*)(dw + i);
    float  c  = nc[m];
    float4 nw, ne;
    nw.x = 0.999f * wv.x + 0.001f * dv.x; ne.x = nw.x / c;
    nw.y = 0.999f * wv.y + 0.001f * dv.y; ne.y = nw.y / c;
    nw.z = 0.999f * wv.z + 0.001f * dv.z; ne.z = nw.z / c;
    nw.w = 0.999f * wv.w + 0.001f * dv.w; ne.w = nw.w / c;
    *(float4*)(out_nw + i) = nw;
    *(float4*)(out_ne + i) = ne;
}

// ---------------- stable compaction (used-first), normalize rows ----------------
__global__ __launch_bounds__(256) void g1_kernel(const float* __restrict__ counts,
                                                 const float* __restrict__ new_emb,
                                                 int* __restrict__ sel,
                                                 float* __restrict__ valid,
                                                 float* __restrict__ n_valid,
                                                 float* __restrict__ normed,
                                                 float* __restrict__ normedT) {
    __shared__ int pre[257];
    int t = threadIdx.x;
    int u = 0;
#pragma unroll
    for (int i = 0; i < 8; ++i) u += (counts[t * 8 + i] > 0.f) ? 1 : 0;
    pre[t] = u;
    __syncthreads();
    if (t == 0) {
        int run = 0;
        for (int i = 0; i < 256; ++i) { int c = pre[i]; pre[i] = run; run += c; }
        pre[256] = run;
    }
    __syncthreads();
    int U = pre[256];
    int base = pre[t];
    int run = 0;
    for (int i = 0; i < 8; ++i) {
        int m = t * 8 + i;
        bool used = counts[m] > 0.f;
        int ur = base + run;
        if (used) {
            if (ur < 128) sel[ur] = m;
            run++;
        } else {
            int pos = U + (m - ur);
            if (pos < 128) sel[pos] = m;
        }
    }
    __syncthreads();
    if (t < 128) valid[t] = (counts[sel[t]] > 0.f) ? 1.f : 0.f;
    __syncthreads();
    if (t == 0) {
        float s = 0.f;
        for (int i = 0; i < 128; ++i) s += valid[i];
        *n_valid = s;
    }
    int w = t >> 6, lane = t & 63;
    for (int r = w; r < 128; r += 4) {
        int sm = sel[r];
        const float* src = new_emb + (size_t)sm * D_DIM;
        float4 a = *(const float4*)(src + lane * 4);
        float4 b = *(const float4*)(src + 256 + lane * 4);
        float s = a.x*a.x + a.y*a.y + a.z*a.z + a.w*a.w
                + b.x*b.x + b.y*b.y + b.z*b.z + b.w*b.w;
#pragma unroll
        for (int o = 32; o > 0; o >>= 1) s += __shfl_xor(s, o, 64);
        float norm = fmaxf(sqrtf(s), 1e-12f);
        float vv = valid[r];
        float4 na, nb;
        na.x = a.x / norm * vv; na.y = a.y / norm * vv;
        na.z = a.z / norm * vv; na.w = a.w / norm * vv;
        nb.x = b.x / norm * vv; nb.y = b.y / norm * vv;
        nb.z = b.z / norm * vv; nb.w = b.w / norm * vv;
        *(float4*)(normed + (size_t)r * D_DIM + lane * 4) = na;
        *(float4*)(normed + (size_t)r * D_DIM + 256 + lane * 4) = nb;
        normedT[(lane * 4 + 0) * 128 + r] = na.x;
        normedT[(lane * 4 + 1) * 128 + r] = na.y;
        normedT[(lane * 4 + 2) * 128 + r] = na.z;
        normedT[(lane * 4 + 3) * 128 + r] = na.w;
        normedT[(256 + lane * 4 + 0) * 128 + r] = nb.x;
        normedT[(256 + lane * 4 + 1) * 128 + r] = nb.y;
        normedT[(256 + lane * 4 + 2) * 128 + r] = nb.z;
        normedT[(256 + lane * 4 + 3) * 128 + r] = nb.w;
    }
}

// ---------------- cosine-sim loss accumulation ----------------
__global__ __launch_bounds__(128) void g2_kernel(const float* __restrict__ normed,
                                                 const float* __restrict__ normedT,
                                                 const float* __restrict__ valid,
                                                 float* __restrict__ ortho_acc) {
    __shared__ float rowi[512];
    __shared__ float red[128];
    int i = blockIdx.x, t = threadIdx.x;
    *(float4*)(rowi + t * 4) = *(const float4*)(normed + (size_t)i * D_DIM + t * 4);
    __syncthreads();
    float dot = 0.f;
    for (int k = 0; k < D_DIM; ++k) dot += rowi[k] * normedT[k * 128 + t];
    float diag = (i == t) ? valid[i] : 0.f;
    float d = dot - diag;
    red[t] = d * d;
    __syncthreads();
    for (int s = 64; s > 0; s >>= 1) {
        if (t < s) red[t] += red[t + s];
        __syncthreads();
    }
    if (t == 0) atomicAdd(ortho_acc, red[0]);
}

// ---------------- final scalars ----------------
__global__ void g3_kernel(const float* __restrict__ sse,
                          const float* __restrict__ ortho_acc,
                          const float* __restrict__ n_valid,
                          float* __restrict__ out3) {
    if (threadIdx.x == 0 && blockIdx.x == 0) {
        float m = *sse / 16777216.f;
        out3[0] = 0.25f * m;
        out3[1] = m;
        float nv = *n_valid;
        out3[2] = *ortho_acc / (nv * nv) * 10.f;
    }
}

extern "C" void kernel_launch(void* const* d_in, const int* in_sizes, int n_in,
                              void* d_out, int out_size, void* d_ws, size_t ws_size,
                              hipStream_t stream) {
    const float* x          = (const float*)d_in[0];
    const float* emb        = (const float*)d_in[1];
    const float* ema_count  = (const float*)d_in[2];
    const float* ema_weight = (const float*)d_in[3];
    float* out = (float*)d_out;
    float* ws  = (float*)d_ws;

    float* counts  = ws + WS_COUNTS;
    float* dw      = ws + WS_DW;
    float* sse     = ws + WS_SSE;
    float* ortho   = ws + WS_ORTHO;
    int*   candcnt = (int*)(ws + WS_CANDCNT);
    float* e2      = ws + WS_E2;
    float* x2      = ws + WS_X2;
    int*   idxws   = (int*)(ws + WS_IDX);
    float* ncn     = ws + WS_NCN;
    int*   sel     = (int*)(ws + WS_SEL);
    float* valid   = ws + WS_VALID;
    float* nvalid  = ws + WS_NVALID;
    float* normed  = ws + WS_NORMED;
    float* normedT = ws + WS_NORMEDT;
    int*   candC   = (int*)(ws + WS_CANDC);
    float* candD   = ws + WS_CANDD;
    unsigned short* xh = (unsigned short*)(ws + WS_XH);
    unsigned short* xl = (unsigned short*)(ws + WS_XL);
    unsigned short* eh = (unsigned short*)(ws + WS_EH);
    unsigned short* el = (unsigned short*)(ws + WS_EL);

    const bool big_ws = ws_size >= (size_t)WS_TOTAL_FLOATS * sizeof(float);

    hipMemsetAsync(ws, 0, (size_t)WS_ZERO_FLOATS * sizeof(float), stream);

    if (big_ws) {
        prep_kernel<<<(M_CODES + N_ROWS) / 4, 256, 0, stream>>>(emb, x, e2, x2, xh, xl, eh, el);
        approx_kernel<<<1024, 256, 0, stream>>>(xh, xl, eh, el, e2, candcnt, candC, candD);
        rerank_kernel<<<N_ROWS / 4, 256, 0, stream>>>(x, emb, e2, x2, candcnt, candC, candD,
                                                      idxws, out + OUT_INDICES);
    } else {
        sq_kernel<<<(M_CODES + N_ROWS) / 4, 256, 0, stream>>>(emb, x, e2, x2);
        argmin_kernel<<<N_ROWS / 64, 256, 0, stream>>>(x, emb, e2, x2, idxws,
                                                       out + OUT_INDICES);
    }

    scatter_kernel<<<N_ROWS / 16, 256, 0, stream>>>(x, emb, idxws, counts, dw, sse,
                                                    out + OUT_QST);

    f1_kernel<<<1, 256, 0, stream>>>(ema_count, counts, out + OUT_NEWCOUNT, ncn);

    f2_kernel<<<(M_CODES * D_DIM) / (256 * 4), 256, 0, stream>>>(ema_weight, dw, ncn,
                                                                 out + OUT_NEWEMB,
                                                                 out + OUT_NEWW);

    g1_kernel<<<1, 256, 0, stream>>>(counts, out + OUT_NEWEMB, sel, valid, nvalid,
                                     normed, normedT);

    g2_kernel<<<128, 128, 0, stream>>>(normed, normedT, valid, ortho);

    g3_kernel<<<1, 64, 0, stream>>>(sse, ortho, nvalid, out + OUT_COMMIT);
}

// Round 3
// 742.159 us; speedup vs baseline: 2.0346x; 1.1312x over previous
//
#include <hip/hip_runtime.h>
#include <math.h>

#define N_ROWS 32768
#define M_CODES 2048
#define D_DIM 512
#define MARGIN 1.2e-3f
#define CAND_CAP 32

// d_out flat offsets (floats), reference return order
#define OUT_QST       0
#define OUT_COMMIT    16777216
#define OUT_CODEBOOK  16777217
#define OUT_ORTHO     16777218
#define OUT_INDICES   16777219
#define OUT_NEWEMB    16809987
#define OUT_NEWCOUNT  17858563
#define OUT_NEWW      17860611

// ---------------- workspace layout (float offsets) ----------------
// zeroed region: [0, WS_ZERO_FLOATS)
#define WS_COUNTS     0            // 2048 floats
#define WS_CURSOR     2048         // 2048 ints
#define WS_SSE        4096         // 1
#define WS_ORTHO      4097         // 1 (+6 pad)
#define WS_CANDCNT    4104         // 32768 ints
#define WS_ZERO_FLOATS 36872
#define WS_E2         36872        // 2048
#define WS_X2         38920        // 32768
#define WS_IDX        71688        // 32768 (int)
#define WS_NCN        104456       // 2048
#define WS_SEL        106504       // 128 (int)
#define WS_VALID      106632       // 128
#define WS_NVALID     106760       // 1 (+7 pad)
#define WS_NORMED     106768       // 65536
#define WS_NORMEDT    172304       // 65536
#define WS_OFFS       237840       // 2048 ints (+8 pad)
#define WS_ORDER      239896       // 32768 ints
#define WS_CANDC      272664       // 32768*32 ints
#define WS_CANDD      1321240      // 32768*32 floats
#define WS_XH         2369816      // 32768*512 shorts (8388608 float slots)
#define WS_EH         10758424     // 2048*512 shorts (524288 float slots)
#define WS_TOTAL_FLOATS 11282712

typedef __attribute__((ext_vector_type(8))) short short8v;
typedef __attribute__((ext_vector_type(4))) float f32x4;

__device__ __forceinline__ unsigned short f2bf(float f) {
    unsigned u = __float_as_uint(f);
    unsigned r = (u + 0x7fffu + ((u >> 16) & 1u)) >> 16;
    return (unsigned short)r;
}
__device__ __forceinline__ int fkey(float f) {
    int b = __float_as_int(f);
    return b >= 0 ? b : (b ^ 0x7fffffff);
}
__device__ __forceinline__ float kinv(int k) {
    int b = k >= 0 ? k : (k ^ 0x7fffffff);
    return __int_as_float(b);
}

#define GLOAD16(g, s) __builtin_amdgcn_global_load_lds( \
    (const __attribute__((address_space(1))) void*)(g), \
    (__attribute__((address_space(3))) void*)(s), 16, 0, 0)

// ---------------- prep: e2/x2 + bf16 (single, round-to-nearest) ----------------
__global__ __launch_bounds__(256) void prep_kernel(const float* __restrict__ emb,
                                                   const float* __restrict__ x,
                                                   float* __restrict__ e2,
                                                   float* __restrict__ x2,
                                                   unsigned short* __restrict__ xh,
                                                   unsigned short* __restrict__ eh) {
    int row  = blockIdx.x * 4 + (threadIdx.x >> 6);
    int lane = threadIdx.x & 63;
    bool is_e = row < M_CODES;
    const float* src = is_e ? (emb + (size_t)row * D_DIM)
                            : (x + (size_t)(row - M_CODES) * D_DIM);
    unsigned short* dh = is_e ? (eh + (size_t)row * D_DIM)
                              : (xh + (size_t)(row - M_CODES) * D_DIM);
    float4 a = *(const float4*)(src + lane * 4);
    float4 b = *(const float4*)(src + 256 + lane * 4);
    float s = a.x*a.x + a.y*a.y + a.z*a.z + a.w*a.w
            + b.x*b.x + b.y*b.y + b.z*b.z + b.w*b.w;
#pragma unroll
    for (int o = 32; o > 0; o >>= 1) s += __shfl_xor(s, o, 64);

    ushort4 h0, h1;
    h0.x = f2bf(a.x); h0.y = f2bf(a.y); h0.z = f2bf(a.z); h0.w = f2bf(a.w);
    h1.x = f2bf(b.x); h1.y = f2bf(b.y); h1.z = f2bf(b.z); h1.w = f2bf(b.w);
    *(ushort4*)(dh + lane * 4)       = h0;
    *(ushort4*)(dh + 256 + lane * 4) = h1;

    if (lane == 0) {
        if (is_e) e2[row] = s;
        else      x2[row - M_CODES] = s;
    }
}

// ---------------- sq only (fallback path) ----------------
__global__ __launch_bounds__(256) void sq_kernel(const float* __restrict__ emb,
                                                 const float* __restrict__ x,
                                                 float* __restrict__ e2,
                                                 float* __restrict__ x2) {
    int row  = blockIdx.x * 4 + (threadIdx.x >> 6);
    int lane = threadIdx.x & 63;
    const float* src = (row < M_CODES) ? (emb + (size_t)row * D_DIM)
                                       : (x + (size_t)(row - M_CODES) * D_DIM);
    float4 a = *(const float4*)(src + lane * 4);
    float4 b = *(const float4*)(src + 256 + lane * 4);
    float s = a.x*a.x + a.y*a.y + a.z*a.z + a.w*a.w
            + b.x*b.x + b.y*b.y + b.z*b.z + b.w*b.w;
#pragma unroll
    for (int o = 32; o > 0; o >>= 1) s += __shfl_xor(s, o, 64);
    if (lane == 0) {
        if (row < M_CODES) e2[row] = s;
        else               x2[row - M_CODES] = s;
    }
}

// ---------------- MFMA bf16 approx distances + candidate collection ----------------
// Block: 128 rows x 512 codes (4 ct-tiles of 128). d = e2[c] - 2*dot_bf16.
// BK=64, k-piece swizzle (p_global = p_lds ^ (row&7)) for conflict-free b128 reads.
__global__ __launch_bounds__(256) void approx_kernel(const unsigned short* __restrict__ xh,
                                                     const unsigned short* __restrict__ eh,
                                                     const float* __restrict__ e2g,
                                                     int* __restrict__ candcnt,
                                                     int* __restrict__ candC,
                                                     float* __restrict__ candD) {
    __shared__ short Ah[128 * 64], Bh[128 * 64];   // 16 KB each, rows of 64 bf16
    __shared__ int rowminI[128];

    const int t = threadIdx.x;
    const int w = t >> 6;        // wave 0..3
    const int l = t & 63;
    const int ml = l & 15;
    const int q  = l >> 4;
    const int rw = (w & 1) * 64;  // wave row block
    const int cw = (w >> 1) * 64; // wave col block

    const int bid = blockIdx.x;
    const int row_tile = (bid >> 5) * 8 + (bid & 7);
    const int sub = (bid >> 3) & 3;
    const int row0 = row_tile * 128;
    const int code_base = sub * 512;

    if (t < 128) rowminI[t] = 0x7fffffff;

    // staging decomposition: round i=0..3, each stages 4 KB (32 rows x 128 B)
    const int grow = l >> 3;                 // row-within-group 0..7
    const int pg8  = (((l & 7) ^ grow)) * 8; // swizzled global piece, element offset

    for (int ct = 0; ct < 4; ++ct) {
        const int code0 = code_base + ct * 128;

        f32x4 acc[4][4];
#pragma unroll
        for (int mi = 0; mi < 4; ++mi)
#pragma unroll
            for (int ni = 0; ni < 4; ++ni) acc[mi][ni] = (f32x4)0.f;

        for (int k0 = 0; k0 < D_DIM; k0 += 64) {
            __syncthreads();
#pragma unroll
            for (int i = 0; i < 4; ++i) {
                int r = i * 32 + w * 8 + grow;
                GLOAD16(xh + (size_t)(row0 + r) * D_DIM + k0 + pg8, &Ah[i * 2048 + w * 512]);
                GLOAD16(eh + (size_t)(code0 + r) * D_DIM + k0 + pg8, &Bh[i * 2048 + w * 512]);
            }
            __syncthreads();

#pragma unroll
            for (int kk = 0; kk < 64; kk += 32) {
                const int pbase = kk >> 3;
                short8v a[4];
#pragma unroll
                for (int mi = 0; mi < 4; ++mi) {
                    int m = rw + mi * 16 + ml;
                    a[mi] = *(const short8v*)(&Ah[m * 64 + ((((pbase + q) ^ (m & 7))) << 3)]);
                }
#pragma unroll
                for (int ni = 0; ni < 4; ++ni) {
                    int n = cw + ni * 16 + ml;
                    short8v b = *(const short8v*)(&Bh[n * 64 + ((((pbase + q) ^ (n & 7))) << 3)]);
#pragma unroll
                    for (int mi = 0; mi < 4; ++mi)
                        acc[mi][ni] = __builtin_amdgcn_mfma_f32_16x16x32_bf16(a[mi], b, acc[mi][ni], 0, 0, 0);
                }
            }
        }

        // epilogue: d = e2 - 2*acc, running per-row min, candidate appends
        float e2v[4];
#pragma unroll
        for (int ni = 0; ni < 4; ++ni) e2v[ni] = e2g[code0 + cw + ni * 16 + ml];

#pragma unroll
        for (int mi = 0; mi < 4; ++mi)
#pragma unroll
            for (int ni = 0; ni < 4; ++ni)
#pragma unroll
                for (int r = 0; r < 4; ++r)
                    acc[mi][ni][r] = e2v[ni] - 2.0f * acc[mi][ni][r];

#pragma unroll
        for (int mi = 0; mi < 4; ++mi)
#pragma unroll
            for (int r = 0; r < 4; ++r) {
                float v = fminf(fminf(acc[mi][0][r], acc[mi][1][r]),
                                fminf(acc[mi][2][r], acc[mi][3][r]));
#pragma unroll
                for (int o = 1; o < 16; o <<= 1) v = fminf(v, __shfl_xor(v, o, 64));
                if (ml == 0) atomicMin(&rowminI[rw + mi * 16 + q * 4 + r], fkey(v));
            }
        __syncthreads();

#pragma unroll
        for (int mi = 0; mi < 4; ++mi)
#pragma unroll
            for (int r = 0; r < 4; ++r) {
                int row_l = rw + mi * 16 + q * 4 + r;
                float rm = kinv(rowminI[row_l]);
                int row_g = row0 + row_l;
#pragma unroll
                for (int ni = 0; ni < 4; ++ni) {
                    float d = acc[mi][ni][r];
                    if (d <= rm + MARGIN) {
                        int pos = atomicAdd(&candcnt[row_g], 1);
                        if (pos < CAND_CAP) {
                            candC[row_g * CAND_CAP + pos] = code0 + cw + ni * 16 + ml;
                            candD[row_g * CAND_CAP + pos] = d;
                        }
                    }
                }
            }
    }
}

// ---------------- exact re-rank + histogram ----------------
__global__ __launch_bounds__(256) void rerank_kernel(const float* __restrict__ x,
                                                     const float* __restrict__ emb,
                                                     const float* __restrict__ e2,
                                                     const float* __restrict__ x2,
                                                     const int* __restrict__ candcnt,
                                                     const int* __restrict__ candC,
                                                     const float* __restrict__ candD,
                                                     float* __restrict__ counts,
                                                     int* __restrict__ idx_out,
                                                     float* __restrict__ idxf_out) {
    const int w = threadIdx.x >> 6;
    const int lane = threadIdx.x & 63;
    const int row = blockIdx.x * 4 + w;

    int cnt = candcnt[row];
    int best_c;

    if (cnt > CAND_CAP) {
        // overflow safety net: exact scan of all codes (lanes parallel over codes)
        const float x2r = x2[row];
        const float* xr = x + (size_t)row * D_DIM;
        float bd = 3.0e38f;
        int   bc = 0x7fffffff;
        for (int c = lane; c < M_CODES; c += 64) {
            const float* er = emb + (size_t)c * D_DIM;
            float dot = 0.f;
            for (int k = 0; k < D_DIM; ++k) dot = fmaf(xr[k], er[k], dot);
            float d = (x2r + e2[c]) - 2.0f * dot;
            if (d < bd || (d == bd && c < bc)) { bd = d; bc = c; }
        }
#pragma unroll
        for (int o = 32; o > 0; o >>= 1) {
            float od = __shfl_xor(bd, o, 64);
            int   oc = __shfl_xor(bc, o, 64);
            if (od < bd || (od == bd && oc < bc)) { bd = od; bc = oc; }
        }
        best_c = bc;
    } else {
        float d = 3.0e38f;
        int   c = 0x7fffffff;
        if (lane < cnt) {
            d = candD[row * CAND_CAP + lane];
            c = candC[row * CAND_CAP + lane];
        }
        float dmin = d;
#pragma unroll
        for (int o = 32; o > 0; o >>= 1) dmin = fminf(dmin, __shfl_xor(dmin, o, 64));

        bool surv = (lane < cnt) && (d <= dmin + MARGIN);
        unsigned long long mask = __ballot(surv);

        if (__popcll(mask) == 1) {
            int src = __ffsll((long long)mask) - 1;
            best_c = __shfl(c, src, 64);
        } else {
            float bd = 3.0e38f;
            int   bc = 0x7fffffff;
            unsigned long long m = mask;
            const float x2r = x2[row];
            const float* xr = x + (size_t)row * D_DIM;
            while (m) {
                int src = __ffsll((long long)m) - 1;
                m &= m - 1;
                int cs = __shfl(c, src, 64);
                const float* er = emb + (size_t)cs * D_DIM;
                float dot = 0.f;
                for (int k = 0; k < D_DIM; ++k) dot = fmaf(xr[k], er[k], dot);
                float t1 = x2r + e2[cs];
                float dex = t1 - 2.0f * dot;
                if (dex < bd || (dex == bd && cs < bc)) { bd = dex; bc = cs; }
            }
            best_c = bc;
        }
    }
    if (lane == 0) {
        idx_out[row] = best_c;
        idxf_out[row] = (float)best_c;
        atomicAdd(&counts[best_c], 1.0f);
    }
}

// ---------------- fallback fp32 argmin (round-1 kernel) ----------------
__global__ __launch_bounds__(256) void argmin_kernel(const float* __restrict__ x,
                                                     const float* __restrict__ emb,
                                                     const float* __restrict__ e2,
                                                     const float* __restrict__ x2,
                                                     int* __restrict__ idx_out,
                                                     float* __restrict__ idxf_out) {
    __shared__ float As[64][36];
    __shared__ float Bs[32][68];
    __shared__ float e2s[64];
    __shared__ float redD[64][17];
    __shared__ int   redI[64][17];

    const int t  = threadIdx.x;
    const int tx = t & 15;
    const int ty = t >> 4;
    const int row0 = blockIdx.x * 64;

    float rmin[4];
    int   ridx[4];
#pragma unroll
    for (int r = 0; r < 4; ++r) { rmin[r] = 3.0e38f; ridx[r] = 0; }

    float x2r[4];
#pragma unroll
    for (int r = 0; r < 4; ++r) x2r[r] = x2[row0 + ty * 4 + r];

    const int lr = t >> 3;
    const int lc = t & 7;

    for (int m0 = 0; m0 < M_CODES; m0 += 64) {
        __syncthreads();
        if (t < 64) e2s[t] = e2[m0 + t];

        float acc[4][4];
#pragma unroll
        for (int r = 0; r < 4; ++r)
#pragma unroll
            for (int c = 0; c < 4; ++c) acc[r][c] = 0.f;

        for (int k0 = 0; k0 < D_DIM; k0 += 32) {
            __syncthreads();
#pragma unroll
            for (int p = 0; p < 2; ++p) {
                int r = p * 32 + lr;
                float4 v = *(const float4*)(x + (size_t)(row0 + r) * D_DIM + k0 + lc * 4);
                *(float4*)(&As[r][lc * 4]) = v;
            }
#pragma unroll
            for (int p = 0; p < 2; ++p) {
                int r = p * 32 + lr;
                float4 v = *(const float4*)(emb + (size_t)(m0 + r) * D_DIM + k0 + lc * 4);
                Bs[lc * 4 + 0][r] = v.x;
                Bs[lc * 4 + 1][r] = v.y;
                Bs[lc * 4 + 2][r] = v.z;
                Bs[lc * 4 + 3][r] = v.w;
            }
            __syncthreads();

#pragma unroll
            for (int kk = 0; kk < 32; kk += 4) {
                float av[4][4], bv[4][4];
#pragma unroll
                for (int r = 0; r < 4; ++r) {
                    float4 a4 = *(const float4*)(&As[ty * 4 + r][kk]);
                    av[r][0] = a4.x; av[r][1] = a4.y; av[r][2] = a4.z; av[r][3] = a4.w;
                }
#pragma unroll
                for (int j = 0; j < 4; ++j) {
                    float4 b4 = *(const float4*)(&Bs[kk + j][tx * 4]);
                    bv[j][0] = b4.x; bv[j][1] = b4.y; bv[j][2] = b4.z; bv[j][3] = b4.w;
                }
#pragma unroll
                for (int j = 0; j < 4; ++j)
#pragma unroll
                    for (int r = 0; r < 4; ++r)
#pragma unroll
                        for (int c = 0; c < 4; ++c)
                            acc[r][c] += av[r][j] * bv[j][c];
            }
        }

#pragma unroll
        for (int c = 0; c < 4; ++c) {
            int mm = tx * 4 + c;
            int m  = m0 + mm;
            float e2v = e2s[mm];
#pragma unroll
            for (int r = 0; r < 4; ++r) {
                float t1 = x2r[r] + e2v;
                float dd  = t1 - 2.0f * acc[r][c];
                if (dd < rmin[r]) { rmin[r] = dd; ridx[r] = m; }
            }
        }
    }

    __syncthreads();
#pragma unroll
    for (int r = 0; r < 4; ++r) {
        redD[ty * 4 + r][tx] = rmin[r];
        redI[ty * 4 + r][tx] = ridx[r];
    }
    __syncthreads();
    if (t < 64) {
        float best = redD[t][0];
        int   bi   = redI[t][0];
#pragma unroll
        for (int i = 1; i < 16; ++i) {
            float dd = redD[t][i];
            int   ii = redI[t][i];
            if (dd < best || (dd == best && ii < bi)) { best = dd; bi = ii; }
        }
        idx_out[row0 + t]  = bi;
        idxf_out[row0 + t] = (float)bi;
    }
}

// ---------------- histogram (fallback path only) ----------------
__global__ __launch_bounds__(256) void hist_kernel(const int* __restrict__ idx,
                                                   float* __restrict__ counts) {
    int r = blockIdx.x * 256 + threadIdx.x;
    atomicAdd(&counts[idx[r]], 1.0f);
}

// ---------------- quant_st + SSE (streaming, no atomic scatter) ----------------
__global__ __launch_bounds__(256) void qst_sse_kernel(const float* __restrict__ x,
                                                      const float* __restrict__ emb,
                                                      const int* __restrict__ idx,
                                                      float* __restrict__ sse,
                                                      float* __restrict__ qst) {
    const int w    = threadIdx.x >> 6;
    const int lane = threadIdx.x & 63;
    const int rowbase = blockIdx.x * 16 + w * 4;
    float loss = 0.f;
    for (int i = 0; i < 4; ++i) {
        const int row = rowbase + i;
        const int m   = idx[row];
#pragma unroll
        for (int j = 0; j < 2; ++j) {
            const int off = j * 256 + lane * 4;
            float4 xv = *(const float4*)(x + (size_t)row * D_DIM + off);
            float4 qv = *(const float4*)(emb + (size_t)m * D_DIM + off);
            float4 qs;
            qs.x = xv.x + (qv.x - xv.x);
            qs.y = xv.y + (qv.y - xv.y);
            qs.z = xv.z + (qv.z - xv.z);
            qs.w = xv.w + (qv.w - xv.w);
            *(float4*)(qst + (size_t)row * D_DIM + off) = qs;
            float dx;
            dx = xv.x - qv.x; loss += dx * dx;
            dx = xv.y - qv.y; loss += dx * dx;
            dx = xv.z - qv.z; loss += dx * dx;
            dx = xv.w - qv.w; loss += dx * dx;
        }
    }
#pragma unroll
    for (int o = 32; o > 0; o >>= 1) loss += __shfl_xor(loss, o, 64);
    if (lane == 0) atomicAdd(sse, loss);
}

// ---------------- EMA count + Laplace normalize ----------------
__global__ __launch_bounds__(256) void f1_kernel(const float* __restrict__ ema_count,
                                                 const float* __restrict__ counts,
                                                 float* __restrict__ out_newcount,
                                                 float* __restrict__ nc_ws) {
    __shared__ float red[256];
    int t = threadIdx.x;
    float raw[8];
    float part = 0.f;
#pragma unroll
    for (int i = 0; i < 8; ++i) {
        int m = t * 8 + i;
        raw[i] = 0.999f * ema_count[m] + 0.001f * counts[m];
        part += raw[i];
    }
    red[t] = part;
    __syncthreads();
    for (int s = 128; s > 0; s >>= 1) {
        if (t < s) red[t] += red[t + s];
        __syncthreads();
    }
    float n = red[0];
    float denom = n + (float)M_CODES * 1e-5f;
#pragma unroll
    for (int i = 0; i < 8; ++i) {
        int m = t * 8 + i;
        float v = (raw[i] + 1e-5f) / denom * n;
        out_newcount[m] = v;
        nc_ws[m] = v;
    }
}

// ---------------- exclusive prefix of counts -> offs ----------------
__global__ __launch_bounds__(256) void scan_kernel(const float* __restrict__ counts,
                                                   int* __restrict__ offs) {
    __shared__ int pre[257];
    int t = threadIdx.x;
    int c[8];
    int s = 0;
#pragma unroll
    for (int i = 0; i < 8; ++i) { c[i] = (int)counts[t * 8 + i]; s += c[i]; }
    pre[t] = s;
    __syncthreads();
    if (t == 0) {
        int run = 0;
        for (int i = 0; i < 256; ++i) { int v = pre[i]; pre[i] = run; run += v; }
        pre[256] = run;
    }
    __syncthreads();
    int base = pre[t];
#pragma unroll
    for (int i = 0; i < 8; ++i) { offs[t * 8 + i] = base; base += c[i]; }
}

// ---------------- fill per-code row lists ----------------
__global__ __launch_bounds__(256) void fill_kernel(const int* __restrict__ idx,
                                                   const int* __restrict__ offs,
                                                   int* __restrict__ cursor,
                                                   int* __restrict__ order) {
    int r = blockIdx.x * 256 + threadIdx.x;
    int m = idx[r];
    int pos = atomicAdd(&cursor[m], 1);
    order[offs[m] + pos] = r;
}

// ---------------- gather-reduce dw + EMA weight + new embedding ----------------
__global__ __launch_bounds__(256) void gather_nw_kernel(const float* __restrict__ x,
                                                        const float* __restrict__ ema_weight,
                                                        const float* __restrict__ ncn,
                                                        const float* __restrict__ counts,
                                                        const int* __restrict__ offs,
                                                        const int* __restrict__ order,
                                                        float* __restrict__ out_ne,
                                                        float* __restrict__ out_nw) {
    const int m = blockIdx.x;
    const int t = threadIdx.x;
    const int beg = offs[m];
    const int end = beg + (int)counts[m];
    float ax = 0.f, ay = 0.f;
    for (int j = beg; j < end; ++j) {
        int r = order[j];
        float2 v = *(const float2*)(x + (size_t)r * D_DIM + t * 2);
        ax += v.x; ay += v.y;
    }
    size_t i = (size_t)m * D_DIM + t * 2;
    float2 wv = *(const float2*)(ema_weight + i);
    float  c  = ncn[m];
    float2 nw, ne;
    nw.x = 0.999f * wv.x + 0.001f * ax; ne.x = nw.x / c;
    nw.y = 0.999f * wv.y + 0.001f * ay; ne.y = nw.y / c;
    *(float2*)(out_nw + i) = nw;
    *(float2*)(out_ne + i) = ne;
}

// ---------------- stable compaction (used-first), normalize rows ----------------
__global__ __launch_bounds__(256) void g1_kernel(const float* __restrict__ counts,
                                                 const float* __restrict__ new_emb,
                                                 int* __restrict__ sel,
                                                 float* __restrict__ valid,
                                                 float* __restrict__ n_valid,
                                                 float* __restrict__ normed,
                                                 float* __restrict__ normedT) {
    __shared__ int pre[257];
    int t = threadIdx.x;
    int u = 0;
#pragma unroll
    for (int i = 0; i < 8; ++i) u += (counts[t * 8 + i] > 0.f) ? 1 : 0;
    pre[t] = u;
    __syncthreads();
    if (t == 0) {
        int run = 0;
        for (int i = 0; i < 256; ++i) { int c = pre[i]; pre[i] = run; run += c; }
        pre[256] = run;
    }
    __syncthreads();
    int U = pre[256];
    int base = pre[t];
    int run = 0;
    for (int i = 0; i < 8; ++i) {
        int m = t * 8 + i;
        bool used = counts[m] > 0.f;
        int ur = base + run;
        if (used) {
            if (ur < 128) sel[ur] = m;
            run++;
        } else {
            int pos = U + (m - ur);
            if (pos < 128) sel[pos] = m;
        }
    }
    __syncthreads();
    if (t < 128) valid[t] = (counts[sel[t]] > 0.f) ? 1.f : 0.f;
    __syncthreads();
    if (t == 0) {
        float s = 0.f;
        for (int i = 0; i < 128; ++i) s += valid[i];
        *n_valid = s;
    }
    int w = t >> 6, lane = t & 63;
    for (int r = w; r < 128; r += 4) {
        int sm = sel[r];
        const float* src = new_emb + (size_t)sm * D_DIM;
        float4 a = *(const float4*)(src + lane * 4);
        float4 b = *(const float4*)(src + 256 + lane * 4);
        float s = a.x*a.x + a.y*a.y + a.z*a.z + a.w*a.w
                + b.x*b.x + b.y*b.y + b.z*b.z + b.w*b.w;
#pragma unroll
        for (int o = 32; o > 0; o >>= 1) s += __shfl_xor(s, o, 64);
        float norm = fmaxf(sqrtf(s), 1e-12f);
        float vv = valid[r];
        float4 na, nb;
        na.x = a.x / norm * vv; na.y = a.y / norm * vv;
        na.z = a.z / norm * vv; na.w = a.w / norm * vv;
        nb.x = b.x / norm * vv; nb.y = b.y / norm * vv;
        nb.z = b.z / norm * vv; nb.w = b.w / norm * vv;
        *(float4*)(normed + (size_t)r * D_DIM + lane * 4) = na;
        *(float4*)(normed + (size_t)r * D_DIM + 256 + lane * 4) = nb;
        normedT[(lane * 4 + 0) * 128 + r] = na.x;
        normedT[(lane * 4 + 1) * 128 + r] = na.y;
        normedT[(lane * 4 + 2) * 128 + r] = na.z;
        normedT[(lane * 4 + 3) * 128 + r] = na.w;
        normedT[(256 + lane * 4 + 0) * 128 + r] = nb.x;
        normedT[(256 + lane * 4 + 1) * 128 + r] = nb.y;
        normedT[(256 + lane * 4 + 2) * 128 + r] = nb.z;
        normedT[(256 + lane * 4 + 3) * 128 + r] = nb.w;
    }
}

// ---------------- cosine-sim loss accumulation ----------------
__global__ __launch_bounds__(128) void g2_kernel(const float* __restrict__ normed,
                                                 const float* __restrict__ normedT,
                                                 const float* __restrict__ valid,
                                                 float* __restrict__ ortho_acc) {
    __shared__ float rowi[512];
    __shared__ float red[128];
    int i = blockIdx.x, t = threadIdx.x;
    *(float4*)(rowi + t * 4) = *(const float4*)(normed + (size_t)i * D_DIM + t * 4);
    __syncthreads();
    float dot = 0.f;
    for (int k = 0; k < D_DIM; ++k) dot += rowi[k] * normedT[k * 128 + t];
    float diag = (i == t) ? valid[i] : 0.f;
    float d = dot - diag;
    red[t] = d * d;
    __syncthreads();
    for (int s = 64; s > 0; s >>= 1) {
        if (t < s) red[t] += red[t + s];
        __syncthreads();
    }
    if (t == 0) atomicAdd(ortho_acc, red[0]);
}

// ---------------- final scalars ----------------
__global__ void g3_kernel(const float* __restrict__ sse,
                          const float* __restrict__ ortho_acc,
                          const float* __restrict__ n_valid,
                          float* __restrict__ out3) {
    if (threadIdx.x == 0 && blockIdx.x == 0) {
        float m = *sse / 16777216.f;
        out3[0] = 0.25f * m;
        out3[1] = m;
        float nv = *n_valid;
        out3[2] = *ortho_acc / (nv * nv) * 10.f;
    }
}

extern "C" void kernel_launch(void* const* d_in, const int* in_sizes, int n_in,
                              void* d_out, int out_size, void* d_ws, size_t ws_size,
                              hipStream_t stream) {
    const float* x          = (const float*)d_in[0];
    const float* emb        = (const float*)d_in[1];
    const float* ema_count  = (const float*)d_in[2];
    const float* ema_weight = (const float*)d_in[3];
    float* out = (float*)d_out;
    float* ws  = (float*)d_ws;

    float* counts  = ws + WS_COUNTS;
    int*   cursor  = (int*)(ws + WS_CURSOR);
    float* sse     = ws + WS_SSE;
    float* ortho   = ws + WS_ORTHO;
    int*   candcnt = (int*)(ws + WS_CANDCNT);
    float* e2      = ws + WS_E2;
    float* x2      = ws + WS_X2;
    int*   idxws   = (int*)(ws + WS_IDX);
    float* ncn     = ws + WS_NCN;
    int*   sel     = (int*)(ws + WS_SEL);
    float* valid   = ws + WS_VALID;
    float* nvalid  = ws + WS_NVALID;
    float* normed  = ws + WS_NORMED;
    float* normedT = ws + WS_NORMEDT;
    int*   offs    = (int*)(ws + WS_OFFS);
    int*   order   = (int*)(ws + WS_ORDER);
    int*   candC   = (int*)(ws + WS_CANDC);
    float* candD   = ws + WS_CANDD;
    unsigned short* xh = (unsigned short*)(ws + WS_XH);
    unsigned short* eh = (unsigned short*)(ws + WS_EH);

    const bool big_ws = ws_size >= (size_t)WS_TOTAL_FLOATS * sizeof(float);

    hipMemsetAsync(ws, 0, (size_t)WS_ZERO_FLOATS * sizeof(float), stream);

    if (big_ws) {
        prep_kernel<<<(M_CODES + N_ROWS) / 4, 256, 0, stream>>>(emb, x, e2, x2, xh, eh);
        approx_kernel<<<1024, 256, 0, stream>>>(xh, eh, e2, candcnt, candC, candD);
        rerank_kernel<<<N_ROWS / 4, 256, 0, stream>>>(x, emb, e2, x2, candcnt, candC, candD,
                                                      counts, idxws, out + OUT_INDICES);
    } else {
        sq_kernel<<<(M_CODES + N_ROWS) / 4, 256, 0, stream>>>(emb, x, e2, x2);
        argmin_kernel<<<N_ROWS / 64, 256, 0, stream>>>(x, emb, e2, x2, idxws,
                                                       out + OUT_INDICES);
        hist_kernel<<<N_ROWS / 256, 256, 0, stream>>>(idxws, counts);
    }

    qst_sse_kernel<<<N_ROWS / 16, 256, 0, stream>>>(x, emb, idxws, sse, out + OUT_QST);

    f1_kernel<<<1, 256, 0, stream>>>(ema_count, counts, out + OUT_NEWCOUNT, ncn);

    scan_kernel<<<1, 256, 0, stream>>>(counts, offs);

    fill_kernel<<<N_ROWS / 256, 256, 0, stream>>>(idxws, offs, cursor, order);

    gather_nw_kernel<<<M_CODES, 256, 0, stream>>>(x, ema_weight, ncn, counts, offs, order,
                                                  out + OUT_NEWEMB, out + OUT_NEWW);

    g1_kernel<<<1, 256, 0, stream>>>(counts, out + OUT_NEWEMB, sel, valid, nvalid,
                                     normed, normedT);

    g2_kernel<<<128, 128, 0, stream>>>(normed, normedT, valid, ortho);

    g3_kernel<<<1, 64, 0, stream>>>(sse, ortho, nvalid, out + OUT_COMMIT);
}